// Round 5
// baseline (12.438 us; speedup 1.0000x reference)
//
#include <hip/hip_runtime.h>
#include <climits>

// Problem constants (match reference)
#define LROW 512
#define OUT_S 65
#define NOUT (OUT_S * OUT_S)   // 4225
#define THRESH 0.2f
#define EPS_F 1e-6f

typedef float f4 __attribute__((ext_vector_type(4)));

// One block per (n,c) row (grid=256 -> 1 block/CU), 256 threads (4 waves),
// ZERO __syncthreads(). R4 lesson: more blocks/waves regressed; fewer waves win.
// first/last-nonzero via ballot+ffs/clz (uniform-index shuffle), only s1/s2
// go through the 6-step butterfly. Per-wave private xn[65] in LDS ordered by
// a same-wave s_waitcnt. Output: 16B-aligned dwordx4 body + scalar head/tail.
__global__ __launch_bounds__(256) void rp_kernel(const float* __restrict__ x,
                                                 float* __restrict__ out) {
    const int row  = blockIdx.x;       // 0 .. N*C-1
    const int tid  = threadIdx.x;      // 0 .. 255
    const int lane = tid & 63;
    const int wid  = tid >> 6;
    const float* xr = x + (size_t)row * LROW;
    const f4* xr4   = reinterpret_cast<const f4*>(xr);   // row base 2KB-aligned

    // ---- each wave loads the full row: 8 floats/lane (2x dwordx4) ----
    const f4 a = xr4[lane];        // x[4*lane .. 4*lane+3]
    const f4 b = xr4[lane + 64];   // x[256+4*lane .. +3]

    // ---- local stats over 8 elements (a-half and b-half kept separate) ----
    int loA = INT_MAX, hiA = -1, loB = INT_MAX, hiB = -1;
    double s1 = 0.0, s2 = 0.0;
    #pragma unroll
    for (int e = 0; e < 4; ++e) {
        const int   k0 = 4 * lane + e;
        const float va = a[e];
        if (va != 0.0f) { loA = min(loA, k0); hiA = max(hiA, k0); }
        s1 += (double)va; s2 += (double)va * (double)va;
        const int   k1 = k0 + 256;
        const float vb = b[e];
        if (vb != 0.0f) { loB = min(loB, k1); hiB = max(hiB, k1); }
        s1 += (double)vb; s2 += (double)vb * (double)vb;
    }

    // ---- first/last via ballot (no butterfly needed for bounds) ----
    const unsigned long long mA = __ballot(loA != INT_MAX);
    const unsigned long long mB = __ballot(loB != INT_MAX);
    const bool anyNZ = (mA | mB) != 0ULL;
    int first = 0, last = -1;
    if (anyNZ) {   // wave-uniform branch; uniform shuffle indices
        first = mA ? __shfl(loA, (int)__ffsll((long long)mA) - 1, 64)
                   : __shfl(loB, (int)__ffsll((long long)mB) - 1, 64);
        last  = mB ? __shfl(hiB, 63 - (int)__clzll((long long)mB), 64)
                   : __shfl(hiA, 63 - (int)__clzll((long long)mA), 64);
    }

    // ---- wave butterfly for s1,s2 only (identical result in every wave) ----
    #pragma unroll
    for (int off = 32; off > 0; off >>= 1) {
        s1 += __shfl_xor(s1, off, 64);
        s2 += __shfl_xor(s2, off, 64);
    }

    const double cnt  = anyNZ ? (double)(last - first + 1) : 1.0;
    const double rcnt = 1.0 / cnt;                   // single fp64 divide
    const float  mean = (float)(s1 * rcnt);          // fp32 mean, like reference
    const double dm   = (double)mean;
    double var = (s2 - 2.0 * dm * s1 + cnt * dm * dm) * rcnt;
    var = var > 0.0 ? var : 0.0;                     // guard tiny negative rounding
    const float stdc = fmaxf(sqrtf((float)var), EPS_F);

    // ---- per-wave private xn[65] (padded): lanes 0..16 own x[0..67] ----
    __shared__ float xnw[4][68];                     // 16B-aligned rows
    if (lane < 17) {
        f4 w;
        #pragma unroll
        for (int e = 0; e < 4; ++e) {
            const int  k = 4 * lane + e;
            const bool m = anyNZ && (k >= first) && (k <= last);
            w[e] = m ? (a[e] - mean) / stdc : 0.0f;  // fp32 ops, like reference
        }
        *reinterpret_cast<f4*>(&xnw[wid][4 * lane]) = w;
    }
    // same-wave LDS RAW: drain lgkm before lanes read their wave's copy
    asm volatile("s_waitcnt lgkmcnt(0)" ::: "memory");

    const float* xn = xnw[wid];
    float* orow = out + (size_t)row * NOUT;

    // row base alignment: (row*4225*4) % 16 cycles; first 16B-aligned elem:
    const int h      = (4 - (row & 3)) & 3;          // head scalars (0..3)
    const int nbody  = (NOUT - h) >> 2;              // full float4 groups
    const int t0     = h + (nbody << 2);             // tail start
    const int ntail  = NOUT - t0;                    // tail scalars (0..3)

    if (tid < h) {                                   // head: k < 3 -> i=0, j=k
        orow[tid] = (fabsf(xn[0] - xn[tid]) < THRESH) ? 1.0f : 0.0f;
    }
    if (tid >= 4 && tid - 4 < ntail) {               // tail
        const int k = t0 + (tid - 4);
        const int i = k / OUT_S;
        const int j = k - i * OUT_S;
        orow[k] = (fabsf(xn[i] - xn[j]) < THRESH) ? 1.0f : 0.0f;
    }

    // body: aligned dwordx4 stores, <=5 iterations/thread
    for (int g = tid; g < nbody; g += 256) {
        const int e0 = h + 4 * g;
        const int i  = e0 / OUT_S;                   // magic-mul division
        int   jj  = e0 - i * OUT_S;
        float xii = xn[i];
        f4 r;
        #pragma unroll
        for (int e = 0; e < 4; ++e) {
            if (jj == OUT_S) { jj = 0; xii = xn[i + 1]; }  // row wrap (<=1/group)
            r[e] = (fabsf(xii - xn[jj]) < THRESH) ? 1.0f : 0.0f;
            ++jj;
        }
        *reinterpret_cast<f4*>(orow + e0) = r;       // provably 16B-aligned
    }
}

extern "C" void kernel_launch(void* const* d_in, const int* in_sizes, int n_in,
                              void* d_out, int out_size, void* d_ws, size_t ws_size,
                              hipStream_t stream) {
    const float* x  = (const float*)d_in[0];
    float*      out = (float*)d_out;
    const int rows  = in_sizes[0] / LROW;   // 64*4 = 256
    rp_kernel<<<rows, 256, 0, stream>>>(x, out);
}

// Round 6
// 12.209 us; speedup vs baseline: 1.0188x; 1.0188x over previous
//
#include <hip/hip_runtime.h>
#include <climits>

// Problem constants (match reference)
#define LROW 512
#define OUT_S 65
#define NOUT (OUT_S * OUT_S)   // 4225
#define THRESH 0.2f
#define EPS_F 1e-6f

typedef float f4 __attribute__((ext_vector_type(4)));

// One block per (n,c) row, 256 threads (4 waves), ZERO __syncthreads().
// Each wave redundantly loads the whole 2KB row (waves 1-3 L1-hit) and
// computes full-row stats with a private 6-step butterfly -> no cross-wave
// exchange. Each wave keeps a private xn[65] in LDS, ordered by a same-wave
// s_waitcnt. Output: 16B-aligned dwordx4 body + scalar head/tail
// (row base alignment cycles with row%4 since 4225 % 4 == 1).
// NOTE (R6): this is the R3 kernel resubmitted VERBATIM as a noise probe —
// R4 (+1.7us) and R5 (+2.7us) "regressions" for strictly-cheaper kernels
// indicate +-1.5-2.5us run-to-run noise around a ~10us launch-overhead floor.
__global__ __launch_bounds__(256) void rp_kernel(const float* __restrict__ x,
                                                 float* __restrict__ out) {
    const int row  = blockIdx.x;       // 0 .. N*C-1
    const int tid  = threadIdx.x;      // 0 .. 255
    const int lane = tid & 63;
    const int wid  = tid >> 6;
    const float* xr = x + (size_t)row * LROW;
    const f4* xr4   = reinterpret_cast<const f4*>(xr);   // row base is 2KB-aligned

    // ---- each wave loads the full row: 8 floats/lane (2x dwordx4) ----
    const f4 a = xr4[lane];        // x[4*lane .. 4*lane+3]
    const f4 b = xr4[lane + 64];   // x[256+4*lane .. 256+4*lane+3]

    // ---- local stats over 8 elements ----
    int lo = INT_MAX, hi = -1;
    double s1 = 0.0, s2 = 0.0;
    #pragma unroll
    for (int e = 0; e < 4; ++e) {
        const int   k0 = 4 * lane + e;
        const float va = a[e];
        if (va != 0.0f) { lo = min(lo, k0); hi = max(hi, k0); }
        s1 += (double)va; s2 += (double)va * (double)va;
        const int   k1 = k0 + 256;
        const float vb = b[e];
        if (vb != 0.0f) { lo = min(lo, k1); hi = max(hi, k1); }
        s1 += (double)vb; s2 += (double)vb * (double)vb;
    }

    // ---- wave butterfly (no barriers; identical result in every wave) ----
    #pragma unroll
    for (int off = 32; off > 0; off >>= 1) {
        lo = min(lo, __shfl_xor(lo, off, 64));
        hi = max(hi, __shfl_xor(hi, off, 64));
        s1 += __shfl_xor(s1, off, 64);
        s2 += __shfl_xor(s2, off, 64);
    }

    const bool   anyNZ = (hi >= 0);
    const double cnt   = anyNZ ? (double)(hi - lo + 1) : 1.0;
    const float  mean  = (float)(s1 / cnt);          // fp32 mean, like reference
    const double dm    = (double)mean;
    double var = (s2 - 2.0 * dm * s1 + cnt * dm * dm) / cnt;
    var = var > 0.0 ? var : 0.0;                     // guard tiny negative rounding
    const float stdc = fmaxf(sqrtf((float)var), EPS_F);

    // ---- per-wave private xn[65] (padded): lanes 0..16 own x[0..67] ----
    __shared__ float xnw[4][68];                     // 272B/wave, 16B-aligned rows
    if (lane < 17) {
        f4 w;
        #pragma unroll
        for (int e = 0; e < 4; ++e) {
            const int  k = 4 * lane + e;
            const bool m = anyNZ && (k >= lo) && (k <= hi);
            w[e] = m ? (a[e] - mean) / stdc : 0.0f;  // fp32 ops, like reference
        }
        *reinterpret_cast<f4*>(&xnw[wid][4 * lane]) = w;
    }
    // same-wave LDS RAW: drain lgkm before any lane reads its wave's copy
    asm volatile("s_waitcnt lgkmcnt(0)" ::: "memory");

    const float* xn = xnw[wid];
    float* orow = out + (size_t)row * NOUT;

    // row base alignment: (row*4225*4) % 16 cycles; first 16B-aligned elem:
    const int h      = (4 - (row & 3)) & 3;          // head scalars (0..3)
    const int nbody  = (NOUT - h) >> 2;              // full float4 groups
    const int t0     = h + (nbody << 2);             // tail start
    const int ntail  = NOUT - t0;                    // tail scalars (0..3)

    if (tid < h) {                                   // head: k < 3 -> i=0, j=k
        orow[tid] = (fabsf(xn[0] - xn[tid]) < THRESH) ? 1.0f : 0.0f;
    }
    if (tid >= 4 && tid - 4 < ntail) {               // tail
        const int k = t0 + (tid - 4);
        const int i = k / OUT_S;
        const int j = k - i * OUT_S;
        orow[k] = (fabsf(xn[i] - xn[j]) < THRESH) ? 1.0f : 0.0f;
    }

    // body: aligned dwordx4 stores, <=5 iterations/thread
    for (int g = tid; g < nbody; g += 256) {
        const int e0 = h + 4 * g;
        const int i  = e0 / OUT_S;                   // magic-mul division
        int   jj  = e0 - i * OUT_S;
        float xii = xn[i];
        f4 r;
        #pragma unroll
        for (int e = 0; e < 4; ++e) {
            if (jj == OUT_S) { jj = 0; xii = xn[i + 1]; }  // row wrap (<=1 per group)
            r[e] = (fabsf(xii - xn[jj]) < THRESH) ? 1.0f : 0.0f;
            ++jj;
        }
        *reinterpret_cast<f4*>(orow + e0) = r;       // provably 16B-aligned
    }
}

extern "C" void kernel_launch(void* const* d_in, const int* in_sizes, int n_in,
                              void* d_out, int out_size, void* d_ws, size_t ws_size,
                              hipStream_t stream) {
    const float* x  = (const float*)d_in[0];
    float*      out = (float*)d_out;
    const int rows  = in_sizes[0] / LROW;   // 64*4 = 256
    rp_kernel<<<rows, 256, 0, stream>>>(x, out);
}